// Round 4
// baseline (56.170 us; speedup 1.0000x reference)
//
#include <hip/hip_runtime.h>
#include <math.h>

#define BATCH 8
#define NN 2048
#define FIN 256
#define FOUT 64
#define ALPHA 0.2f

typedef __attribute__((ext_vector_type(8))) short bf16x8;
typedef __attribute__((ext_vector_type(4))) float f32x4;

static __device__ __forceinline__ unsigned short f2bf(float f) {
  unsigned int u = __float_as_uint(f);
  u += 0x7fffu + ((u >> 16) & 1u);
  return (unsigned short)(u >> 16);
}
static __device__ __forceinline__ float bf2f(unsigned short h) {
  return __uint_as_float(((unsigned int)h) << 16);
}
static __device__ __forceinline__ void gload16(const void* g, void* l) {
  __builtin_amdgcn_global_load_lds(
      (const __attribute__((address_space(1))) unsigned int*)g,
      (__attribute__((address_space(3))) unsigned int*)l, 16, 0, 0);
}

// ---------------------------------------------------------------------------
// K1: h = x@W via MFMA (hi/lo bf16 split), el/er via shuffle reduce, then
// emit per-64-row pre-swizzled h "staging images" for K2. (unchanged)
// ---------------------------------------------------------------------------
__global__ __launch_bounds__(256) void k1_h(
    const float* __restrict__ x, const float* __restrict__ W,
    const float* __restrict__ a, float* __restrict__ el,
    float* __restrict__ er, unsigned char* __restrict__ hS) {
  __shared__ __align__(16) unsigned short lds[32768];  // 64 KB
  const int t = threadIdx.x;
  const int wv = t >> 6;
  const int l = t & 63;
  const int l15 = l & 15;
  const int kg = l >> 4;

  // phase 0: stage W as bf16 hi/lo planes, XOR-swizzled:
  // u16 idx = plane*16384 + o*256 + ((k>>3)^(o&7))*8 + (k&7)
  {
    const float4* W4 = (const float4*)W;
    #pragma unroll
    for (int i = 0; i < 16; ++i) {
      int f = t + i * 256;            // float4 index, 0..4095
      float4 v = W4[f];
      int k = f >> 4;                 // W row 0..255
      int ob = (f & 15) * 4;
      float vv[4] = {v.x, v.y, v.z, v.w};
      #pragma unroll
      for (int c = 0; c < 4; ++c) {
        int o = ob + c;
        unsigned short hi = f2bf(vv[c]);
        unsigned short lo = f2bf(vv[c] - bf2f(hi));
        int idx = o * 256 + (((k >> 3) ^ (o & 7)) * 8) + (k & 7);
        lds[idx] = hi;
        lds[16384 + idx] = lo;
      }
    }
  }
  __syncthreads();

  const int row = blockIdx.x * 64 + wv * 16 + l15;
  f32x4 acc[4] = {{0.f,0.f,0.f,0.f},{0.f,0.f,0.f,0.f},
                  {0.f,0.f,0.f,0.f},{0.f,0.f,0.f,0.f}};
  const float* xrow = x + (size_t)row * FIN;

  #pragma unroll
  for (int ks = 0; ks < 8; ++ks) {
    int k0 = ks * 32;
    float4 xa = *(const float4*)(xrow + k0 + kg * 8);
    float4 xb = *(const float4*)(xrow + k0 + kg * 8 + 4);
    float xv[8] = {xa.x, xa.y, xa.z, xa.w, xb.x, xb.y, xb.z, xb.w};
    bf16x8 ahi, alo;
    #pragma unroll
    for (int j = 0; j < 8; ++j) {
      unsigned short hi = f2bf(xv[j]);
      unsigned short lo = f2bf(xv[j] - bf2f(hi));
      ahi[j] = (short)hi;
      alo[j] = (short)lo;
    }
    int kgidx = ks * 4 + kg;
    #pragma unroll
    for (int ot = 0; ot < 4; ++ot) {
      int o = ot * 16 + l15;
      int base = o * 256 + ((kgidx ^ (o & 7)) * 8);
      bf16x8 bhi = *(const bf16x8*)&lds[base];
      bf16x8 blo = *(const bf16x8*)&lds[16384 + base];
      acc[ot] = __builtin_amdgcn_mfma_f32_16x16x32_bf16(ahi, bhi, acc[ot], 0, 0, 0);
      acc[ot] = __builtin_amdgcn_mfma_f32_16x16x32_bf16(ahi, blo, acc[ot], 0, 0, 0);
      acc[ot] = __builtin_amdgcn_mfma_f32_16x16x32_bf16(alo, bhi, acc[ot], 0, 0, 0);
    }
  }

  // el/er: reduce across the 16 col-lanes (same kg group)
  float aLv[4], aRv[4];
  #pragma unroll
  for (int ot = 0; ot < 4; ++ot) {
    aLv[ot] = a[ot * 16 + l15];
    aRv[ot] = a[64 + ot * 16 + l15];
  }
  #pragma unroll
  for (int jj = 0; jj < 4; ++jj) {
    float pl = 0.f, pr = 0.f;
    #pragma unroll
    for (int ot = 0; ot < 4; ++ot) {
      pl += acc[ot][jj] * aLv[ot];
      pr += acc[ot][jj] * aRv[ot];
    }
    #pragma unroll
    for (int s = 1; s < 16; s <<= 1) {
      pl += __shfl_xor(pl, s);
      pr += __shfl_xor(pr, s);
    }
    if (l15 == 0) {
      int grow = blockIdx.x * 64 + wv * 16 + kg * 4 + jj;
      el[grow] = pl;
      er[grow] = pr;
    }
  }

  // phase 2: hi/lo split of h, scatter into the image layout (alias lds):
  // u16 idx = ((ks2*2+plane)*64 + o)*32 + (kg2 ^ ((o>>1)&3))*8 + j
  __syncthreads();
  #pragma unroll
  for (int ot = 0; ot < 4; ++ot) {
    int o = ot * 16 + l15;
    int xorv = (o >> 1) & 3;
    #pragma unroll
    for (int jj = 0; jj < 4; ++jj) {
      int m_loc = wv * 16 + kg * 4 + jj;
      int ks2 = m_loc >> 5;
      int kg2 = (m_loc >> 3) & 3;
      int j = m_loc & 7;
      int kgp = kg2 ^ xorv;
      float v = acc[ot][jj];
      unsigned short hi = f2bf(v);
      unsigned short lo = f2bf(v - bf2f(hi));
      int base = ((ks2 * 2 + 0) * 64 + o) * 32 + kgp * 8 + j;
      lds[base] = hi;
      lds[base + 2048] = lo;  // plane stride = 64*32 u16
    }
  }
  __syncthreads();

  // dump 16KB image contiguously to global
  {
    const uint4* src = (const uint4*)(const void*)lds;
    uint4* dst = (uint4*)(hS + (size_t)blockIdx.x * 16384);
    #pragma unroll
    for (int i = 0; i < 4; ++i) dst[t + i * 256] = src[t + i * 256];
  }
}

// ---------------------------------------------------------------------------
// K2: masked-softmax attention as MFMA GEMM, counted-vmcnt pipeline (T3/T4).
// Grid: 512 blocks x 256 thr (4 waves: 2 m-pairs x 2 row-waves), 2 blocks/CU.
// Per iteration a wave issues exactly 16 VMEM ops: 8 global_load_lds (h-image
// chunk tc+1) + 8 reg loads (adj/er for tc+2, 2-deep). Wait is vmcnt(16):
// "everything older than this iteration's issues is done" -- robust to any
// intra-iteration instruction reorder. Two raw barriers per iteration.
// ---------------------------------------------------------------------------
__global__ __launch_bounds__(256, 2) void k2_attn(
    const int* __restrict__ adj, const unsigned char* __restrict__ hS,
    const float* __restrict__ el, const float* __restrict__ er,
    float* __restrict__ out) {
  __shared__ __align__(1024) unsigned char buf[2][2][16384];
  const int t = threadIdx.x;
  const int wv = t >> 6;
  const int l = t & 63;
  const int l15 = l & 15;
  const int kg = l >> 4;
  const int pair = wv >> 1;   // which m-half
  const int pw = wv & 1;      // row sub-block within pair

  // XCD-bijective swizzle: 512 blocks, 64/XCD -> each XCD sees one batch
  int bid = blockIdx.x;
  int swz = (bid & 7) * 64 + (bid >> 3);
  int b = swz >> 6;
  int n0 = (swz & 63) * 32;
  const int nrow = n0 + pw * 16 + l15;

  const float eL = el[b * NN + nrow];
  const float* erp = er + b * NN + pair * 1024;
  const int* arow = adj + (size_t)b * NN * NN + (size_t)nrow * NN + pair * 1024;
  const unsigned char* hSb =
      hS + (size_t)b * 32 * 16384 + (size_t)pair * 16 * 16384;

  const int laneoff = l15 * 64 + ((kg ^ ((l >> 1) & 3)) * 16);

  f32x4 acc[4] = {{0.f,0.f,0.f,0.f},{0.f,0.f,0.f,0.f},
                  {0.f,0.f,0.f,0.f},{0.f,0.f,0.f,0.f}};
  float Sacc = 0.f;

  int4 av0[4], av1[4], av2[4];
  float4 ev0[4], ev1[4], ev2[4];

#define STAGE(tcc) {                                                       \
    const unsigned char* src_ = hSb + (size_t)(tcc) * 16384;               \
    unsigned char* dst_ = &buf[pair][(tcc) & 1][0];                        \
    _Pragma("unroll")                                                      \
    for (int s_ = 0; s_ < 8; ++s_) {                                       \
      int seg_ = pw * 8 + s_;                                              \
      gload16(src_ + seg_ * 1024 + l * 16, dst_ + seg_ * 1024);            \
    } }

#define LOADR(A, E, tcc) {                                                 \
    int mb_ = (tcc) * 64;                                                  \
    _Pragma("unroll")                                                      \
    for (int kx_ = 0; kx_ < 2; ++kx_) {                                    \
      A[kx_*2+0] = *(const int4*)(arow + mb_ + kx_*32 + kg*8);             \
      A[kx_*2+1] = *(const int4*)(arow + mb_ + kx_*32 + kg*8 + 4);         \
      E[kx_*2+0] = *(const float4*)(erp + mb_ + kx_*32 + kg*8);            \
      E[kx_*2+1] = *(const float4*)(erp + mb_ + kx_*32 + kg*8 + 4);        \
    } }

  // prologue: chunk 0 staged + R for chunks 0 and 1; full drain once.
  STAGE(0);
  LOADR(av0, ev0, 0);
  LOADR(av1, ev1, 1);
  asm volatile("s_waitcnt vmcnt(0)" ::: "memory");
  __builtin_amdgcn_s_barrier();

  #pragma unroll
  for (int tc = 0; tc < 16; ++tc) {
    if (tc < 15) STAGE(tc + 1);          // 8 gloads -> buf[(tc+1)&1]
    if (tc < 14) LOADR(av2, ev2, tc + 2); // 8 reg loads, 2 iterations ahead

    // counted wait: allow exactly this iteration's issues to stay in flight
    if (tc < 14)      { asm volatile("s_waitcnt vmcnt(16)" ::: "memory"); }
    else if (tc < 15) { asm volatile("s_waitcnt vmcnt(8)"  ::: "memory"); }
    else              { asm volatile("s_waitcnt vmcnt(0)"  ::: "memory"); }
    __builtin_amdgcn_s_barrier();        // buf[tc&1] ready for all waves

    const unsigned char* cur = &buf[pair][tc & 1][0];
    #pragma unroll
    for (int ks = 0; ks < 2; ++ks) {
      int aarr[8] = {av0[ks*2].x, av0[ks*2].y, av0[ks*2].z, av0[ks*2].w,
                     av0[ks*2+1].x, av0[ks*2+1].y, av0[ks*2+1].z, av0[ks*2+1].w};
      float earr[8] = {ev0[ks*2].x, ev0[ks*2].y, ev0[ks*2].z, ev0[ks*2].w,
                       ev0[ks*2+1].x, ev0[ks*2+1].y, ev0[ks*2+1].z, ev0[ks*2+1].w};
      bf16x8 af;
      #pragma unroll
      for (int j = 0; j < 8; ++j) {
        float e = eL + earr[j];
        e = fmaxf(e, ALPHA * e);          // leaky relu
        float w = (aarr[j] > 0) ? __expf(e) : 0.f;
        unsigned short hb = f2bf(w);
        af[j] = (short)hb;
        Sacc += bf2f(hb);                 // denominator from the SAME rounded w
      }
      #pragma unroll
      for (int ot = 0; ot < 4; ++ot) {
        const unsigned char* p = cur + ks * 8192 + ot * 1024 + laneoff;
        bf16x8 bhi = *(const bf16x8*)p;
        bf16x8 blo = *(const bf16x8*)(p + 4096);
        acc[ot] = __builtin_amdgcn_mfma_f32_16x16x32_bf16(af, bhi, acc[ot], 0, 0, 0);
        acc[ot] = __builtin_amdgcn_mfma_f32_16x16x32_bf16(af, blo, acc[ot], 0, 0, 0);
      }
    }

    asm volatile("" ::: "memory");       // pin ds_reads above release barrier
    __builtin_amdgcn_s_barrier();        // release buf[tc&1] for overwrite

    // static register rotation (fully unrolled -> SSA, no movs)
    #pragma unroll
    for (int i = 0; i < 4; ++i) {
      av0[i] = av1[i]; ev0[i] = ev1[i];
      av1[i] = av2[i]; ev1[i] = ev2[i];
    }
  }

  // S partial: reduce across kg groups within this wave (replicated over kg)
  float Sred = Sacc + __shfl_xor(Sacc, 16);
  Sred += __shfl_xor(Sred, 32);

  // cross-pair combine via LDS: pair-1 waves publish {acc[16], Sred},
  // pair-0 waves (same rows) add them in. slot stride 96 B (16B-aligned).
  {
    unsigned char* cb = &buf[0][0][0];
    const int slot = pw * 64 + l;
    if (pair == 1) {
      float* dst = (float*)(cb + slot * 96);
      *(f32x4*)(dst + 0)  = acc[0];
      *(f32x4*)(dst + 4)  = acc[1];
      *(f32x4*)(dst + 8)  = acc[2];
      *(f32x4*)(dst + 12) = acc[3];
      dst[16] = Sred;
    }
    __syncthreads();
    if (pair == 1) return;
    const float* src = (const float*)(cb + slot * 96);
    #pragma unroll
    for (int ot = 0; ot < 4; ++ot) {
      f32x4 o4 = *(const f32x4*)(src + ot * 4);
      acc[ot] += o4;
    }
    Sred += src[16];
  }

  // epilogue (pair 0 only): normalize, ELU, store
  float Sj[4];
  #pragma unroll
  for (int jj = 0; jj < 4; ++jj) Sj[jj] = __shfl(Sred, kg * 4 + jj);
  #pragma unroll
  for (int ot = 0; ot < 4; ++ot) {
    #pragma unroll
    for (int jj = 0; jj < 4; ++jj) {
      float v = acc[ot][jj] / Sj[jj];
      float res = v > 0.f ? v : expm1f(v);
      out[((size_t)b * NN + n0 + pw * 16 + kg * 4 + jj) * FOUT + ot * 16 + l15] = res;
    }
  }
}

extern "C" void kernel_launch(void* const* d_in, const int* in_sizes, int n_in,
                              void* d_out, int out_size, void* d_ws, size_t ws_size,
                              hipStream_t stream) {
  const float* x   = (const float*)d_in[0];
  const int*   adj = (const int*)d_in[1];
  const float* W   = (const float*)d_in[2];
  const float* a   = (const float*)d_in[3];
  float* out = (float*)d_out;

  // ws layout: hS images (8*32*16KB = 4MB) | el (64KB) | er (64KB)
  unsigned char* hS = (unsigned char*)d_ws;
  float* el = (float*)(hS + (size_t)BATCH * 32 * 16384);
  float* er = el + BATCH * NN;

  hipLaunchKernelGGL(k1_h, dim3(256), dim3(256), 0, stream, x, W, a, el, er, hS);
  hipLaunchKernelGGL(k2_attn, dim3(512), dim3(256), 0, stream, adj, hS, el, er, out);
}

// Round 6
// 50.654 us; speedup vs baseline: 1.1089x; 1.1089x over previous
//
#include <hip/hip_runtime.h>
#include <math.h>

#define BATCH 8
#define NN 2048
#define FIN 256
#define FOUT 64
#define ALPHA 0.2f

typedef __attribute__((ext_vector_type(8))) short bf16x8;
typedef __attribute__((ext_vector_type(4))) float f32x4;

static __device__ __forceinline__ unsigned short f2bf(float f) {
  unsigned int u = __float_as_uint(f);
  u += 0x7fffu + ((u >> 16) & 1u);
  return (unsigned short)(u >> 16);
}
static __device__ __forceinline__ float bf2f(unsigned short h) {
  return __uint_as_float(((unsigned int)h) << 16);
}
static __device__ __forceinline__ void gload16(const void* g, void* l) {
  __builtin_amdgcn_global_load_lds(
      (const __attribute__((address_space(1))) unsigned int*)g,
      (__attribute__((address_space(3))) unsigned int*)l, 16, 0, 0);
}

// ---------------------------------------------------------------------------
// K1: h = x@W via MFMA (hi/lo bf16 split), el/er via shuffle reduce, then
// emit per-64-row pre-swizzled h "staging images" for K2. (unchanged)
// ---------------------------------------------------------------------------
__global__ __launch_bounds__(256) void k1_h(
    const float* __restrict__ x, const float* __restrict__ W,
    const float* __restrict__ a, float* __restrict__ el,
    float* __restrict__ er, unsigned char* __restrict__ hS) {
  __shared__ __align__(16) unsigned short lds[32768];  // 64 KB
  const int t = threadIdx.x;
  const int wv = t >> 6;
  const int l = t & 63;
  const int l15 = l & 15;
  const int kg = l >> 4;

  // phase 0: stage W as bf16 hi/lo planes, XOR-swizzled:
  // u16 idx = plane*16384 + o*256 + ((k>>3)^(o&7))*8 + (k&7)
  {
    const float4* W4 = (const float4*)W;
    #pragma unroll
    for (int i = 0; i < 16; ++i) {
      int f = t + i * 256;            // float4 index, 0..4095
      float4 v = W4[f];
      int k = f >> 4;                 // W row 0..255
      int ob = (f & 15) * 4;
      float vv[4] = {v.x, v.y, v.z, v.w};
      #pragma unroll
      for (int c = 0; c < 4; ++c) {
        int o = ob + c;
        unsigned short hi = f2bf(vv[c]);
        unsigned short lo = f2bf(vv[c] - bf2f(hi));
        int idx = o * 256 + (((k >> 3) ^ (o & 7)) * 8) + (k & 7);
        lds[idx] = hi;
        lds[16384 + idx] = lo;
      }
    }
  }
  __syncthreads();

  const int row = blockIdx.x * 64 + wv * 16 + l15;
  f32x4 acc[4] = {{0.f,0.f,0.f,0.f},{0.f,0.f,0.f,0.f},
                  {0.f,0.f,0.f,0.f},{0.f,0.f,0.f,0.f}};
  const float* xrow = x + (size_t)row * FIN;

  #pragma unroll
  for (int ks = 0; ks < 8; ++ks) {
    int k0 = ks * 32;
    float4 xa = *(const float4*)(xrow + k0 + kg * 8);
    float4 xb = *(const float4*)(xrow + k0 + kg * 8 + 4);
    float xv[8] = {xa.x, xa.y, xa.z, xa.w, xb.x, xb.y, xb.z, xb.w};
    bf16x8 ahi, alo;
    #pragma unroll
    for (int j = 0; j < 8; ++j) {
      unsigned short hi = f2bf(xv[j]);
      unsigned short lo = f2bf(xv[j] - bf2f(hi));
      ahi[j] = (short)hi;
      alo[j] = (short)lo;
    }
    int kgidx = ks * 4 + kg;
    #pragma unroll
    for (int ot = 0; ot < 4; ++ot) {
      int o = ot * 16 + l15;
      int base = o * 256 + ((kgidx ^ (o & 7)) * 8);
      bf16x8 bhi = *(const bf16x8*)&lds[base];
      bf16x8 blo = *(const bf16x8*)&lds[16384 + base];
      acc[ot] = __builtin_amdgcn_mfma_f32_16x16x32_bf16(ahi, bhi, acc[ot], 0, 0, 0);
      acc[ot] = __builtin_amdgcn_mfma_f32_16x16x32_bf16(ahi, blo, acc[ot], 0, 0, 0);
      acc[ot] = __builtin_amdgcn_mfma_f32_16x16x32_bf16(alo, bhi, acc[ot], 0, 0, 0);
    }
  }

  // el/er: reduce across the 16 col-lanes (same kg group)
  float aLv[4], aRv[4];
  #pragma unroll
  for (int ot = 0; ot < 4; ++ot) {
    aLv[ot] = a[ot * 16 + l15];
    aRv[ot] = a[64 + ot * 16 + l15];
  }
  #pragma unroll
  for (int jj = 0; jj < 4; ++jj) {
    float pl = 0.f, pr = 0.f;
    #pragma unroll
    for (int ot = 0; ot < 4; ++ot) {
      pl += acc[ot][jj] * aLv[ot];
      pr += acc[ot][jj] * aRv[ot];
    }
    #pragma unroll
    for (int s = 1; s < 16; s <<= 1) {
      pl += __shfl_xor(pl, s);
      pr += __shfl_xor(pr, s);
    }
    if (l15 == 0) {
      int grow = blockIdx.x * 64 + wv * 16 + kg * 4 + jj;
      el[grow] = pl;
      er[grow] = pr;
    }
  }

  // phase 2: hi/lo split of h, scatter into the image layout (alias lds):
  // u16 idx = ((ks2*2+plane)*64 + o)*32 + (kg2 ^ ((o>>1)&3))*8 + j
  __syncthreads();
  #pragma unroll
  for (int ot = 0; ot < 4; ++ot) {
    int o = ot * 16 + l15;
    int xorv = (o >> 1) & 3;
    #pragma unroll
    for (int jj = 0; jj < 4; ++jj) {
      int m_loc = wv * 16 + kg * 4 + jj;
      int ks2 = m_loc >> 5;
      int kg2 = (m_loc >> 3) & 3;
      int j = m_loc & 7;
      int kgp = kg2 ^ xorv;
      float v = acc[ot][jj];
      unsigned short hi = f2bf(v);
      unsigned short lo = f2bf(v - bf2f(hi));
      int base = ((ks2 * 2 + 0) * 64 + o) * 32 + kgp * 8 + j;
      lds[base] = hi;
      lds[base + 2048] = lo;  // plane stride = 64*32 u16
    }
  }
  __syncthreads();

  // dump 16KB image contiguously to global
  {
    const uint4* src = (const uint4*)(const void*)lds;
    uint4* dst = (uint4*)(hS + (size_t)blockIdx.x * 16384);
    #pragma unroll
    for (int i = 0; i < 4; ++i) dst[t + i * 256] = src[t + i * 256];
  }
}

// ---------------------------------------------------------------------------
// K2: masked-softmax attention as MFMA GEMM — barrier-free per-wave pipelines
// (round-5 structure) + hi/lo-split attention weights for fp32-grade P.
// Each wave owns 32 n-rows x a disjoint 512-m window, private 2x8KB LDS
// double-buffer, counted per-wave vmcnt (no loop barriers). Per chunk:
// w = exp(leaky(el+er)) masked; whi/wlo bf16 planes; PV uses
// whi*Bhi + whi*Blo + wlo*Bhi (wlo*Blo ~2^-18, dropped); S sums whi+wlo.
// ---------------------------------------------------------------------------
__global__ __launch_bounds__(256, 2) void k2_attn(
    const int* __restrict__ adj, const unsigned char* __restrict__ hS,
    const float* __restrict__ el, const float* __restrict__ er,
    float* __restrict__ out) {
  __shared__ __align__(1024) unsigned char buf[4][2][8192];  // 64 KB
  const int t = threadIdx.x;
  const int wv = t >> 6;
  const int l = t & 63;
  const int l15 = l & 15;
  const int kg = l >> 4;

  // XCD-bijective swizzle: 512 blocks, 64/XCD -> each XCD sees one batch
  int bid = blockIdx.x;
  int swz = (bid & 7) * 64 + (bid >> 3);
  int b = swz >> 6;
  int n0 = (swz & 63) * 32;

  const int row0 = n0 + l15;        // rt=0 rows
  const int row1 = n0 + 16 + l15;   // rt=1 rows
  const float eL0 = el[b * NN + row0];
  const float eL1 = el[b * NN + row1];
  const int* arow0 = adj + (size_t)b * NN * NN + (size_t)row0 * NN + wv * 512;
  const int* arow1 = adj + (size_t)b * NN * NN + (size_t)row1 * NN + wv * 512;
  const float* erp = er + b * NN + wv * 512;
  // wave's 16 8KB chunks (32 m each), pre-swizzled image
  const unsigned char* hW = hS + (size_t)b * 32 * 16384 + (size_t)wv * 16 * 8192;

  const int laneoff = l15 * 64 + ((kg ^ ((l >> 1) & 3)) * 16);

  f32x4 acc[2][4] = {{{0.f,0.f,0.f,0.f},{0.f,0.f,0.f,0.f},
                      {0.f,0.f,0.f,0.f},{0.f,0.f,0.f,0.f}},
                     {{0.f,0.f,0.f,0.f},{0.f,0.f,0.f,0.f},
                      {0.f,0.f,0.f,0.f},{0.f,0.f,0.f,0.f}}};
  float S0 = 0.f, S1 = 0.f;

  int4 av[3][4];
  float4 ev[3][2];

#define STAGE(cc) {                                                        \
    const unsigned char* src_ = hW + (size_t)(cc) * 8192;                  \
    unsigned char* dst_ = &buf[wv][(cc) & 1][0];                           \
    _Pragma("unroll")                                                      \
    for (int s_ = 0; s_ < 8; ++s_)                                         \
      gload16(src_ + s_ * 1024 + l * 16, dst_ + s_ * 1024);                \
  }
#define LOADR(slot, cc) {                                                  \
    int mb_ = (cc) * 32;                                                   \
    av[slot][0] = *(const int4*)(arow0 + mb_ + kg * 8);                    \
    av[slot][1] = *(const int4*)(arow0 + mb_ + kg * 8 + 4);                \
    av[slot][2] = *(const int4*)(arow1 + mb_ + kg * 8);                    \
    av[slot][3] = *(const int4*)(arow1 + mb_ + kg * 8 + 4);                \
    ev[slot][0] = *(const float4*)(erp + mb_ + kg * 8);                    \
    ev[slot][1] = *(const float4*)(erp + mb_ + kg * 8 + 4);                \
  }

  // prologue
  STAGE(0);
  LOADR(0, 0);
  LOADR(1, 1);

  #pragma unroll
  for (int c = 0; c < 16; ++c) {
    if (c < 15) STAGE(c + 1);            // 8 gload_lds -> private buf
    if (c < 14) LOADR((c + 2) % 3, c + 2);  // 6 reg loads, 2 slots ahead

    // allow exactly this iteration's issues to remain in flight (per-wave,
    // no barrier needed: gload_lds completion visible to own wave)
    if (c < 14)      { asm volatile("s_waitcnt vmcnt(14)" ::: "memory"); }
    else if (c < 15) { asm volatile("s_waitcnt vmcnt(8)"  ::: "memory"); }
    else             { asm volatile("s_waitcnt vmcnt(0)"  ::: "memory"); }

    const int sl = c % 3;
    int a0[8] = {av[sl][0].x, av[sl][0].y, av[sl][0].z, av[sl][0].w,
                 av[sl][1].x, av[sl][1].y, av[sl][1].z, av[sl][1].w};
    int a1[8] = {av[sl][2].x, av[sl][2].y, av[sl][2].z, av[sl][2].w,
                 av[sl][3].x, av[sl][3].y, av[sl][3].z, av[sl][3].w};
    float ee[8] = {ev[sl][0].x, ev[sl][0].y, ev[sl][0].z, ev[sl][0].w,
                   ev[sl][1].x, ev[sl][1].y, ev[sl][1].z, ev[sl][1].w};

    bf16x8 af0h, af0l, af1h, af1l;
    #pragma unroll
    for (int j = 0; j < 8; ++j) {
      float e0 = eL0 + ee[j];
      e0 = fmaxf(e0, ALPHA * e0);
      float w0 = (a0[j] > 0) ? __expf(e0) : 0.f;
      unsigned short h0 = f2bf(w0);
      float w0h = bf2f(h0);
      unsigned short l0 = f2bf(w0 - w0h);
      af0h[j] = (short)h0;
      af0l[j] = (short)l0;
      S0 += w0h + bf2f(l0);               // denom == effective numer weight

      float e1 = eL1 + ee[j];
      e1 = fmaxf(e1, ALPHA * e1);
      float w1 = (a1[j] > 0) ? __expf(e1) : 0.f;
      unsigned short h1 = f2bf(w1);
      float w1h = bf2f(h1);
      unsigned short l1 = f2bf(w1 - w1h);
      af1h[j] = (short)h1;
      af1l[j] = (short)l1;
      S1 += w1h + bf2f(l1);
    }

    const unsigned char* cur = &buf[wv][c & 1][0];
    #pragma unroll
    for (int ot = 0; ot < 4; ++ot) {
      const unsigned char* p = cur + ot * 1024 + laneoff;
      bf16x8 bhi = *(const bf16x8*)p;
      bf16x8 blo = *(const bf16x8*)(p + 4096);
      acc[0][ot] = __builtin_amdgcn_mfma_f32_16x16x32_bf16(af0h, bhi, acc[0][ot], 0, 0, 0);
      acc[0][ot] = __builtin_amdgcn_mfma_f32_16x16x32_bf16(af0h, blo, acc[0][ot], 0, 0, 0);
      acc[0][ot] = __builtin_amdgcn_mfma_f32_16x16x32_bf16(af0l, bhi, acc[0][ot], 0, 0, 0);
      acc[1][ot] = __builtin_amdgcn_mfma_f32_16x16x32_bf16(af1h, bhi, acc[1][ot], 0, 0, 0);
      acc[1][ot] = __builtin_amdgcn_mfma_f32_16x16x32_bf16(af1h, blo, acc[1][ot], 0, 0, 0);
      acc[1][ot] = __builtin_amdgcn_mfma_f32_16x16x32_bf16(af1l, bhi, acc[1][ot], 0, 0, 0);
    }
  }
#undef STAGE
#undef LOADR

  // per-wave S reduce across kg groups (replicates row-l15 denom to all lanes)
  S0 += __shfl_xor(S0, 16); S0 += __shfl_xor(S0, 32);
  S1 += __shfl_xor(S1, 16); S1 += __shfl_xor(S1, 32);

  // cross-wave combine of m-window partials: waves 1..3 publish, wave 0 sums
  __syncthreads();   // all waves done with their buffers
  float* cb = (float*)(void*)&buf[0][0][0];
  if (wv > 0) {
    float* dst = cb + ((wv - 1) * 64 + l) * 36;
    #pragma unroll
    for (int ot = 0; ot < 4; ++ot) {
      *(f32x4*)(dst + ot * 4)      = acc[0][ot];
      *(f32x4*)(dst + 16 + ot * 4) = acc[1][ot];
    }
    dst[32] = S0;
    dst[33] = S1;
  }
  __syncthreads();
  if (wv != 0) return;

  #pragma unroll
  for (int p = 0; p < 3; ++p) {
    const float* src = cb + (p * 64 + l) * 36;
    #pragma unroll
    for (int ot = 0; ot < 4; ++ot) {
      acc[0][ot] += *(const f32x4*)(src + ot * 4);
      acc[1][ot] += *(const f32x4*)(src + 16 + ot * 4);
    }
    S0 += src[32];
    S1 += src[33];
  }

  float Sj0[4], Sj1[4];
  #pragma unroll
  for (int jj = 0; jj < 4; ++jj) {
    Sj0[jj] = __shfl(S0, kg * 4 + jj);
    Sj1[jj] = __shfl(S1, kg * 4 + jj);
  }
  #pragma unroll
  for (int ot = 0; ot < 4; ++ot) {
    #pragma unroll
    for (int jj = 0; jj < 4; ++jj) {
      float v0 = acc[0][ot][jj] / Sj0[jj];
      float r0 = v0 > 0.f ? v0 : expm1f(v0);
      out[((size_t)b * NN + n0 + kg * 4 + jj) * FOUT + ot * 16 + l15] = r0;
      float v1 = acc[1][ot][jj] / Sj1[jj];
      float r1 = v1 > 0.f ? v1 : expm1f(v1);
      out[((size_t)b * NN + n0 + 16 + kg * 4 + jj) * FOUT + ot * 16 + l15] = r1;
    }
  }
}

extern "C" void kernel_launch(void* const* d_in, const int* in_sizes, int n_in,
                              void* d_out, int out_size, void* d_ws, size_t ws_size,
                              hipStream_t stream) {
  const float* x   = (const float*)d_in[0];
  const int*   adj = (const int*)d_in[1];
  const float* W   = (const float*)d_in[2];
  const float* a   = (const float*)d_in[3];
  float* out = (float*)d_out;

  // ws layout: hS images (8*32*16KB = 4MB) | el (64KB) | er (64KB)
  unsigned char* hS = (unsigned char*)d_ws;
  float* el = (float*)(hS + (size_t)BATCH * 32 * 16384);
  float* er = el + BATCH * NN;

  hipLaunchKernelGGL(k1_h, dim3(256), dim3(256), 0, stream, x, W, a, el, er, hS);
  hipLaunchKernelGGL(k2_attn, dim3(512), dim3(256), 0, stream, adj, hS, el, er, out);
}

// Round 7
// 50.050 us; speedup vs baseline: 1.1223x; 1.0121x over previous
//
#include <hip/hip_runtime.h>
#include <math.h>

#define BATCH 8
#define NN 2048
#define FIN 256
#define FOUT 64
#define ALPHA 0.2f

typedef __attribute__((ext_vector_type(8))) short bf16x8;
typedef __attribute__((ext_vector_type(4))) float f32x4;

static __device__ __forceinline__ unsigned short f2bf(float f) {
  unsigned int u = __float_as_uint(f);
  u += 0x7fffu + ((u >> 16) & 1u);
  return (unsigned short)(u >> 16);
}
static __device__ __forceinline__ float bf2f(unsigned short h) {
  return __uint_as_float(((unsigned int)h) << 16);
}

// ---------------------------------------------------------------------------
// K1: h = x@W via MFMA (hi/lo bf16 split), el/er via shuffle reduce, then
// emit per-64-row pre-swizzled h "staging images" for K2. (unchanged)
// ---------------------------------------------------------------------------
__global__ __launch_bounds__(256) void k1_h(
    const float* __restrict__ x, const float* __restrict__ W,
    const float* __restrict__ a, float* __restrict__ el,
    float* __restrict__ er, unsigned char* __restrict__ hS) {
  __shared__ __align__(16) unsigned short lds[32768];  // 64 KB
  const int t = threadIdx.x;
  const int wv = t >> 6;
  const int l = t & 63;
  const int l15 = l & 15;
  const int kg = l >> 4;

  // phase 0: stage W as bf16 hi/lo planes, XOR-swizzled:
  // u16 idx = plane*16384 + o*256 + ((k>>3)^(o&7))*8 + (k&7)
  {
    const float4* W4 = (const float4*)W;
    #pragma unroll
    for (int i = 0; i < 16; ++i) {
      int f = t + i * 256;            // float4 index, 0..4095
      float4 v = W4[f];
      int k = f >> 4;                 // W row 0..255
      int ob = (f & 15) * 4;
      float vv[4] = {v.x, v.y, v.z, v.w};
      #pragma unroll
      for (int c = 0; c < 4; ++c) {
        int o = ob + c;
        unsigned short hi = f2bf(vv[c]);
        unsigned short lo = f2bf(vv[c] - bf2f(hi));
        int idx = o * 256 + (((k >> 3) ^ (o & 7)) * 8) + (k & 7);
        lds[idx] = hi;
        lds[16384 + idx] = lo;
      }
    }
  }
  __syncthreads();

  const int row = blockIdx.x * 64 + wv * 16 + l15;
  f32x4 acc[4] = {{0.f,0.f,0.f,0.f},{0.f,0.f,0.f,0.f},
                  {0.f,0.f,0.f,0.f},{0.f,0.f,0.f,0.f}};
  const float* xrow = x + (size_t)row * FIN;

  #pragma unroll
  for (int ks = 0; ks < 8; ++ks) {
    int k0 = ks * 32;
    float4 xa = *(const float4*)(xrow + k0 + kg * 8);
    float4 xb = *(const float4*)(xrow + k0 + kg * 8 + 4);
    float xv[8] = {xa.x, xa.y, xa.z, xa.w, xb.x, xb.y, xb.z, xb.w};
    bf16x8 ahi, alo;
    #pragma unroll
    for (int j = 0; j < 8; ++j) {
      unsigned short hi = f2bf(xv[j]);
      unsigned short lo = f2bf(xv[j] - bf2f(hi));
      ahi[j] = (short)hi;
      alo[j] = (short)lo;
    }
    int kgidx = ks * 4 + kg;
    #pragma unroll
    for (int ot = 0; ot < 4; ++ot) {
      int o = ot * 16 + l15;
      int base = o * 256 + ((kgidx ^ (o & 7)) * 8);
      bf16x8 bhi = *(const bf16x8*)&lds[base];
      bf16x8 blo = *(const bf16x8*)&lds[16384 + base];
      acc[ot] = __builtin_amdgcn_mfma_f32_16x16x32_bf16(ahi, bhi, acc[ot], 0, 0, 0);
      acc[ot] = __builtin_amdgcn_mfma_f32_16x16x32_bf16(ahi, blo, acc[ot], 0, 0, 0);
      acc[ot] = __builtin_amdgcn_mfma_f32_16x16x32_bf16(alo, bhi, acc[ot], 0, 0, 0);
    }
  }

  // el/er: reduce across the 16 col-lanes (same kg group)
  float aLv[4], aRv[4];
  #pragma unroll
  for (int ot = 0; ot < 4; ++ot) {
    aLv[ot] = a[ot * 16 + l15];
    aRv[ot] = a[64 + ot * 16 + l15];
  }
  #pragma unroll
  for (int jj = 0; jj < 4; ++jj) {
    float pl = 0.f, pr = 0.f;
    #pragma unroll
    for (int ot = 0; ot < 4; ++ot) {
      pl += acc[ot][jj] * aLv[ot];
      pr += acc[ot][jj] * aRv[ot];
    }
    #pragma unroll
    for (int s = 1; s < 16; s <<= 1) {
      pl += __shfl_xor(pl, s);
      pr += __shfl_xor(pr, s);
    }
    if (l15 == 0) {
      int grow = blockIdx.x * 64 + wv * 16 + kg * 4 + jj;
      el[grow] = pl;
      er[grow] = pr;
    }
  }

  // phase 2: hi/lo split of h, scatter into the image layout (alias lds):
  // u16 idx = ((ks2*2+plane)*64 + o)*32 + (kg2 ^ ((o>>1)&3))*8 + j
  __syncthreads();
  #pragma unroll
  for (int ot = 0; ot < 4; ++ot) {
    int o = ot * 16 + l15;
    int xorv = (o >> 1) & 3;
    #pragma unroll
    for (int jj = 0; jj < 4; ++jj) {
      int m_loc = wv * 16 + kg * 4 + jj;
      int ks2 = m_loc >> 5;
      int kg2 = (m_loc >> 3) & 3;
      int j = m_loc & 7;
      int kgp = kg2 ^ xorv;
      float v = acc[ot][jj];
      unsigned short hi = f2bf(v);
      unsigned short lo = f2bf(v - bf2f(hi));
      int base = ((ks2 * 2 + 0) * 64 + o) * 32 + kgp * 8 + j;
      lds[base] = hi;
      lds[base + 2048] = lo;  // plane stride = 64*32 u16
    }
  }
  __syncthreads();

  // dump 16KB image contiguously to global
  {
    const uint4* src = (const uint4*)(const void*)lds;
    uint4* dst = (uint4*)(hS + (size_t)blockIdx.x * 16384);
    #pragma unroll
    for (int i = 0; i < 4; ++i) dst[t + i * 256] = src[t + i * 256];
  }
}

// ---------------------------------------------------------------------------
// K2: masked-softmax attention as MFMA GEMM — register-direct B-fragments.
// Each wave owns 32 n-rows x a disjoint 512-m window (16 chunks of 32 m).
// B-fragments (h hi/lo) are loaded STRAIGHT from the pre-swizzled global
// image into VGPRs (L2-resident: 64 same-batch blocks/XCD share 512KB) with
// a 1-chunk-ahead named prefetch; adj/er rotate 2 ahead. No LDS staging, no
// barriers, no asm in the main loop — compiler inserts precise vmcnt per
// register use. LDS only holds the end-of-kernel cross-wave combine.
// ---------------------------------------------------------------------------
__global__ __launch_bounds__(256, 2) void k2_attn(
    const int* __restrict__ adj, const unsigned char* __restrict__ hS,
    const float* __restrict__ el, const float* __restrict__ er,
    float* __restrict__ out) {
  __shared__ __align__(16) float cb[3 * 64 * 36];  // 27.6 KB combine buffer
  const int t = threadIdx.x;
  const int wv = t >> 6;
  const int l = t & 63;
  const int l15 = l & 15;
  const int kg = l >> 4;

  // XCD-bijective swizzle: 512 blocks, 64/XCD -> each XCD sees one batch
  int bid = blockIdx.x;
  int swz = (bid & 7) * 64 + (bid >> 3);
  int b = swz >> 6;
  int n0 = (swz & 63) * 32;

  const int row0 = n0 + l15;        // rt=0 rows
  const int row1 = n0 + 16 + l15;   // rt=1 rows
  const float eL0 = el[b * NN + row0];
  const float eL1 = el[b * NN + row1];
  const int* arow0 = adj + (size_t)b * NN * NN + (size_t)row0 * NN + wv * 512;
  const int* arow1 = adj + (size_t)b * NN * NN + (size_t)row1 * NN + wv * 512;
  const float* erp = er + b * NN + wv * 512;
  // wave's 16 8KB chunks (32 m each), pre-swizzled image; frag addr is
  // lane-indexed: chunk*8192 + ot*1024 + laneoff (+4096 for lo plane)
  const unsigned char* hW = hS + (size_t)b * 32 * 16384 + (size_t)wv * 16 * 8192;
  const int laneoff = l15 * 64 + ((kg ^ ((l >> 1) & 3)) * 16);

  f32x4 acc[2][4] = {{{0.f,0.f,0.f,0.f},{0.f,0.f,0.f,0.f},
                      {0.f,0.f,0.f,0.f},{0.f,0.f,0.f,0.f}},
                     {{0.f,0.f,0.f,0.f},{0.f,0.f,0.f,0.f},
                      {0.f,0.f,0.f,0.f},{0.f,0.f,0.f,0.f}}};
  float S0 = 0.f, S1 = 0.f;

  bf16x8 curH[4], curL[4], nxtH[4], nxtL[4];
  int4 av[3][4];
  float4 ev[3][2];

#define LOADB(H, L, cc) {                                                  \
    const unsigned char* p_ = hW + (size_t)(cc) * 8192 + laneoff;          \
    _Pragma("unroll")                                                      \
    for (int ot_ = 0; ot_ < 4; ++ot_) {                                    \
      H[ot_] = *(const bf16x8*)(p_ + ot_ * 1024);                          \
      L[ot_] = *(const bf16x8*)(p_ + ot_ * 1024 + 4096);                   \
    } }
#define LOADR(slot, cc) {                                                  \
    int mb_ = (cc) * 32;                                                   \
    av[slot][0] = *(const int4*)(arow0 + mb_ + kg * 8);                    \
    av[slot][1] = *(const int4*)(arow0 + mb_ + kg * 8 + 4);                \
    av[slot][2] = *(const int4*)(arow1 + mb_ + kg * 8);                    \
    av[slot][3] = *(const int4*)(arow1 + mb_ + kg * 8 + 4);                \
    ev[slot][0] = *(const float4*)(erp + mb_ + kg * 8);                    \
    ev[slot][1] = *(const float4*)(erp + mb_ + kg * 8 + 4);                \
  }

  // prologue: chunk-0 fragments + adj/er for chunks 0 and 1
  LOADB(curH, curL, 0);
  LOADR(0, 0);
  LOADR(1, 1);

  #pragma unroll
  for (int c = 0; c < 16; ++c) {
    if (c < 15) LOADB(nxtH, nxtL, c + 1);   // prefetch next B-frags (L2)
    if (c < 14) LOADR((c + 2) % 3, c + 2);  // adj/er 2 chunks ahead (HBM/L3)

    const int sl = c % 3;
    int a0[8] = {av[sl][0].x, av[sl][0].y, av[sl][0].z, av[sl][0].w,
                 av[sl][1].x, av[sl][1].y, av[sl][1].z, av[sl][1].w};
    int a1[8] = {av[sl][2].x, av[sl][2].y, av[sl][2].z, av[sl][2].w,
                 av[sl][3].x, av[sl][3].y, av[sl][3].z, av[sl][3].w};
    float ee[8] = {ev[sl][0].x, ev[sl][0].y, ev[sl][0].z, ev[sl][0].w,
                   ev[sl][1].x, ev[sl][1].y, ev[sl][1].z, ev[sl][1].w};

    bf16x8 af0h, af0l, af1h, af1l;
    #pragma unroll
    for (int j = 0; j < 8; ++j) {
      float e0 = eL0 + ee[j];
      e0 = fmaxf(e0, ALPHA * e0);
      float w0 = (a0[j] > 0) ? __expf(e0) : 0.f;
      unsigned short h0 = f2bf(w0);
      float w0h = bf2f(h0);
      unsigned short l0 = f2bf(w0 - w0h);
      af0h[j] = (short)h0;
      af0l[j] = (short)l0;
      S0 += w0h + bf2f(l0);               // denom == effective numer weight

      float e1 = eL1 + ee[j];
      e1 = fmaxf(e1, ALPHA * e1);
      float w1 = (a1[j] > 0) ? __expf(e1) : 0.f;
      unsigned short h1 = f2bf(w1);
      float w1h = bf2f(h1);
      unsigned short l1 = f2bf(w1 - w1h);
      af1h[j] = (short)h1;
      af1l[j] = (short)l1;
      S1 += w1h + bf2f(l1);
    }

    #pragma unroll
    for (int ot = 0; ot < 4; ++ot) {
      acc[0][ot] = __builtin_amdgcn_mfma_f32_16x16x32_bf16(af0h, curH[ot], acc[0][ot], 0, 0, 0);
      acc[0][ot] = __builtin_amdgcn_mfma_f32_16x16x32_bf16(af0h, curL[ot], acc[0][ot], 0, 0, 0);
      acc[0][ot] = __builtin_amdgcn_mfma_f32_16x16x32_bf16(af0l, curH[ot], acc[0][ot], 0, 0, 0);
      acc[1][ot] = __builtin_amdgcn_mfma_f32_16x16x32_bf16(af1h, curH[ot], acc[1][ot], 0, 0, 0);
      acc[1][ot] = __builtin_amdgcn_mfma_f32_16x16x32_bf16(af1h, curL[ot], acc[1][ot], 0, 0, 0);
      acc[1][ot] = __builtin_amdgcn_mfma_f32_16x16x32_bf16(af1l, curH[ot], acc[1][ot], 0, 0, 0);
    }

    if (c < 15) {
      #pragma unroll
      for (int ot = 0; ot < 4; ++ot) {
        curH[ot] = nxtH[ot];   // SSA under full unroll: renames, no movs
        curL[ot] = nxtL[ot];
      }
    }
  }
#undef LOADB
#undef LOADR

  // per-wave S reduce across kg groups (replicates row-l15 denom to all lanes)
  S0 += __shfl_xor(S0, 16); S0 += __shfl_xor(S0, 32);
  S1 += __shfl_xor(S1, 16); S1 += __shfl_xor(S1, 32);

  // cross-wave combine of m-window partials: waves 1..3 publish, wave 0 sums
  __syncthreads();
  if (wv > 0) {
    float* dst = cb + ((wv - 1) * 64 + l) * 36;
    #pragma unroll
    for (int ot = 0; ot < 4; ++ot) {
      *(f32x4*)(dst + ot * 4)      = acc[0][ot];
      *(f32x4*)(dst + 16 + ot * 4) = acc[1][ot];
    }
    dst[32] = S0;
    dst[33] = S1;
  }
  __syncthreads();
  if (wv != 0) return;

  #pragma unroll
  for (int p = 0; p < 3; ++p) {
    const float* src = cb + (p * 64 + l) * 36;
    #pragma unroll
    for (int ot = 0; ot < 4; ++ot) {
      acc[0][ot] += *(const f32x4*)(src + ot * 4);
      acc[1][ot] += *(const f32x4*)(src + 16 + ot * 4);
    }
    S0 += src[32];
    S1 += src[33];
  }

  float Sj0[4], Sj1[4];
  #pragma unroll
  for (int jj = 0; jj < 4; ++jj) {
    Sj0[jj] = __shfl(S0, kg * 4 + jj);
    Sj1[jj] = __shfl(S1, kg * 4 + jj);
  }
  #pragma unroll
  for (int ot = 0; ot < 4; ++ot) {
    #pragma unroll
    for (int jj = 0; jj < 4; ++jj) {
      float v0 = acc[0][ot][jj] / Sj0[jj];
      float r0 = v0 > 0.f ? v0 : expm1f(v0);
      out[((size_t)b * NN + n0 + kg * 4 + jj) * FOUT + ot * 16 + l15] = r0;
      float v1 = acc[1][ot][jj] / Sj1[jj];
      float r1 = v1 > 0.f ? v1 : expm1f(v1);
      out[((size_t)b * NN + n0 + 16 + kg * 4 + jj) * FOUT + ot * 16 + l15] = r1;
    }
  }
}

extern "C" void kernel_launch(void* const* d_in, const int* in_sizes, int n_in,
                              void* d_out, int out_size, void* d_ws, size_t ws_size,
                              hipStream_t stream) {
  const float* x   = (const float*)d_in[0];
  const int*   adj = (const int*)d_in[1];
  const float* W   = (const float*)d_in[2];
  const float* a   = (const float*)d_in[3];
  float* out = (float*)d_out;

  // ws layout: hS images (8*32*16KB = 4MB) | el (64KB) | er (64KB)
  unsigned char* hS = (unsigned char*)d_ws;
  float* el = (float*)(hS + (size_t)BATCH * 32 * 16384);
  float* er = el + BATCH * NN;

  hipLaunchKernelGGL(k1_h, dim3(256), dim3(256), 0, stream, x, W, a, el, er, hS);
  hipLaunchKernelGGL(k2_attn, dim3(512), dim3(256), 0, stream, adj, hS, el, er, out);
}